// Round 12
// baseline (856.823 us; speedup 1.0000x reference)
//
#include <hip/hip_runtime.h>

#define DIM 128
#define NA 4096
#define NWORDS 16384
#define MAXNZ 256
#define KW 23
#define PAD 11

// ---------------- gather rows: out[i][:] = tab[idx[i]][:] (float4) ----------------
__global__ void k_gather(float* __restrict__ out, const float* __restrict__ tab,
                         const int* __restrict__ idx) {
  int t = blockIdx.x * blockDim.x + threadIdx.x;   // over n*32 float4s
  int r = t >> 5, c = t & 31;
  ((float4*)out)[t] = ((const float4*)(tab + (size_t)idx[r] * DIM))[c];
}

// ---------------- adjacency scan -> per-row (col,val) lists ----------------
__global__ void k_adj_scan(int* __restrict__ cnt, int* __restrict__ colx,
                           float* __restrict__ valx, const float* __restrict__ adj) {
  int w = threadIdx.x >> 6, lane = threadIdx.x & 63;
  int row = blockIdx.x * 4 + w;
  const float4* ar = (const float4*)(adj + (size_t)row * NA);
  int count = 0;
  unsigned long long ltm = (1ull << lane) - 1ull;
  for (int c4 = lane; c4 < NA / 4; c4 += 64) {
    float4 v = ar[c4];
    #pragma unroll
    for (int e = 0; e < 4; ++e) {
      float ve = e == 0 ? v.x : e == 1 ? v.y : e == 2 ? v.z : v.w;
      unsigned long long m = __ballot(ve != 0.0f);
      if (ve != 0.0f) {
        int off = count + (int)__popcll(m & ltm);
        if (off < MAXNZ) { colx[row * MAXNZ + off] = c4 * 4 + e; valx[row * MAXNZ + off] = ve; }
      }
      count += (int)__popcll(m);
    }
  }
  if (lane == 0) cnt[row] = count;
}

// ---------------- C[M,128] = relu(A[M,128] @ W[128,128]^T + b) ----------------
__global__ __launch_bounds__(256) void k_linear_relu(
    float* __restrict__ out, const float* __restrict__ A,
    const float* __restrict__ W, const float* __restrict__ bias) {
  __shared__ float As[64 * 132];
  __shared__ float Ws[64 * 132];
  int mt = blockIdx.x >> 1, nt = blockIdx.x & 1;
  int r0 = mt * 64, c0 = nt * 64;
  int tid = threadIdx.x;
  for (int q = tid; q < 64 * 32; q += 256) {
    int row = q >> 5, c4 = q & 31;
    *(float4*)&As[row * 132 + c4 * 4] = *(const float4*)&A[(size_t)(r0 + row) * DIM + c4 * 4];
    *(float4*)&Ws[row * 132 + c4 * 4] = *(const float4*)&W[(size_t)(c0 + row) * DIM + c4 * 4];
  }
  __syncthreads();
  int rgr = tid & 15, cgr = tid >> 4;
  float acc[4][4] = {};
  #pragma unroll 4
  for (int k4 = 0; k4 < 32; ++k4) {
    int kk = ((k4 + rgr) & 31) * 4;
    float4 a[4], w[4];
    #pragma unroll
    for (int i = 0; i < 4; ++i) a[i] = *(const float4*)&As[(rgr * 4 + i) * 132 + kk];
    #pragma unroll
    for (int j = 0; j < 4; ++j) w[j] = *(const float4*)&Ws[(cgr * 4 + j) * 132 + kk];
    #pragma unroll
    for (int i = 0; i < 4; ++i)
      #pragma unroll
      for (int j = 0; j < 4; ++j)
        acc[i][j] += a[i].x * w[j].x + a[i].y * w[j].y + a[i].z * w[j].z + a[i].w * w[j].w;
  }
  #pragma unroll
  for (int i = 0; i < 4; ++i) {
    int r = r0 + rgr * 4 + i;
    int c = c0 + cgr * 4;
    float4 bv = *(const float4*)&bias[c];
    float4 o;
    o.x = acc[i][0] + bv.x; o.y = acc[i][1] + bv.y;
    o.z = acc[i][2] + bv.z; o.w = acc[i][3] + bv.w;
    o.x = o.x > 0.f ? o.x : 0.f; o.y = o.y > 0.f ? o.y : 0.f;
    o.z = o.z > 0.f ? o.z : 0.f; o.w = o.w > 0.f ? o.w : 0.f;
    *(float4*)&out[(size_t)r * DIM + c] = o;
  }
}

// ---------------- xs[r][:] += sum_i val_i * hs[col_i][:] ----------------
__global__ void k_spmm(float* __restrict__ xs, const float* __restrict__ hs,
                       const int* __restrict__ cnt, const int* __restrict__ colx,
                       const float* __restrict__ valx, const float* __restrict__ adj) {
  __shared__ int scol[MAXNZ];
  __shared__ float sval[MAXNZ];
  int r = blockIdx.x, d = threadIdx.x;
  int n = cnt[r];
  int m = (n <= MAXNZ) ? n : 0;
  for (int i = d; i < m; i += 128) {
    scol[i] = colx[r * MAXNZ + i];
    sval[i] = valx[r * MAXNZ + i];
  }
  __syncthreads();
  float acc = xs[(size_t)r * DIM + d];
  if (n <= MAXNZ) {
    for (int i = 0; i < n; ++i)
      acc += sval[i] * hs[(size_t)scol[i] * DIM + d];
  } else {              // safety fallback, statistically never taken
    for (int c = 0; c < NA; ++c) {
      float a = adj[(size_t)r * NA + c];
      if (a != 0.f) acc += a * hs[(size_t)c * DIM + d];
    }
  }
  xs[(size_t)r * DIM + d] = acc;
}

// ---------------- column mean (scaled), atomic partials ----------------
__global__ void k_mean(float* __restrict__ out, const float* __restrict__ in,
                       int rows_per_block, float scale) {
  __shared__ float red[256];
  int d = threadIdx.x & 127, half = threadIdx.x >> 7;
  int r0 = blockIdx.x * rows_per_block;
  float acc = 0.f;
  for (int r = r0 + half; r < r0 + rows_per_block; r += 2)
    acc += in[(size_t)r * DIM + d];
  red[threadIdx.x] = acc;
  __syncthreads();
  if (half == 0) atomicAdd(&out[d], (acc + red[threadIdx.x + 128]) * scale);
}

// ---------------- 23x23 conv (1 channel) + bias + leaky relu ----------------
// Thread = 4 cols x 2 rows. Per dy: each row window = 7 contiguous
// ds_read_b128 (lanes 0-31 read consecutive float4s of one row = all 32
// banks once = conflict-free; pattern verified rounds 5/7/9). Rows roll
// (win1 at dy becomes win0 at dy+1) -> 168 b128/thread vs round-9's 690
// b32 (DS-issue was the binder: 64k cyc/CU). SROA-SAFE: scalar float
// arrays + literal indices ONLY, components copied from named float4
// temps; NO pointer/reference to locals (round-10 spill cause: f4get ref).
#define CROWS 16
#define TROWS 38      // CROWS + 22
#define TCOLS 152     // cols -12..139 (left pad 12 for 16B alignment)
#define TSTR  152
template<int GATHER>
__global__ __launch_bounds__(256, 4) void k_conv(
    float* __restrict__ out, const float* __restrict__ in,
    const int* __restrict__ words, const float* __restrict__ emb,
    const float* __restrict__ cw, const float* __restrict__ cb) {
  __shared__ float tile[TROWS * TSTR];   // 23.1 KB
  int r0 = blockIdx.x * CROWS;
  int tid = threadIdx.x;
  for (int p = tid; p < TROWS * TCOLS; p += 256) {
    int rr = p / TCOLS, cc = p - rr * TCOLS;
    int gr = r0 - PAD + rr, gc = cc - 12;
    float v = 0.f;
    if ((unsigned)gr < NWORDS && (unsigned)gc < DIM) {
      if (GATHER) v = emb[(size_t)words[gr] * DIM + gc];
      else        v = in[(size_t)gr * DIM + gc];
    }
    tile[rr * TSTR + cc] = v;
  }
  __syncthreads();
  int cg = tid & 31, rg = tid >> 5;   // 32 col-groups x 8 row-groups
  int c0 = cg * 4;                    // output cols c0..c0+3
  int orow = rg * 2;                  // local output rows orow, orow+1
  float acc0[4] = {0.f, 0.f, 0.f, 0.f};
  float acc1[4] = {0.f, 0.f, 0.f, 0.f};
  float win0[28], win1[28];           // scalar arrays, literal indices only

#define LOADW(W, trow) { \
    const float4* p_ = (const float4*)&tile[(trow) * TSTR + c0]; \
    _Pragma("unroll") for (int q = 0; q < 7; ++q) { \
      float4 t_ = p_[q]; \
      W[q * 4 + 0] = t_.x; W[q * 4 + 1] = t_.y; \
      W[q * 4 + 2] = t_.z; W[q * 4 + 3] = t_.w; } }

#define CSTEP(W0, W1, wbase) { \
    _Pragma("unroll") for (int dx = 0; dx < 23; ++dx) { \
      float wv = (wbase)[dx]; \
      _Pragma("unroll") for (int j = 0; j < 4; ++j) { \
        acc0[j] = __builtin_fmaf(wv, W0[1 + j + dx], acc0[j]); \
        acc1[j] = __builtin_fmaf(wv, W1[1 + j + dx], acc1[j]); } } }

  LOADW(win0, orow + 0)
  LOADW(win1, orow + 1)
  const float* wr = cw;
  #pragma unroll 1
  for (int d2 = 0; d2 < 11; ++d2) {
    int dy = d2 * 2;
    CSTEP(win0, win1, wr)              // dy   (rows orow+dy, orow+dy+1)
    LOADW(win0, orow + dy + 2)
    CSTEP(win1, win0, wr + KW)         // dy+1 (rows orow+dy+1, orow+dy+2)
    LOADW(win1, orow + dy + 3)
    wr += 2 * KW;
  }
  CSTEP(win0, win1, wr)                // dy = 22
#undef LOADW
#undef CSTEP

  float bias = cb[0];
  float4 o0, o1;
  float x;
  x = acc0[0] + bias; o0.x = x > 0.f ? x : 0.01f * x;
  x = acc0[1] + bias; o0.y = x > 0.f ? x : 0.01f * x;
  x = acc0[2] + bias; o0.z = x > 0.f ? x : 0.01f * x;
  x = acc0[3] + bias; o0.w = x > 0.f ? x : 0.01f * x;
  x = acc1[0] + bias; o1.x = x > 0.f ? x : 0.01f * x;
  x = acc1[1] + bias; o1.y = x > 0.f ? x : 0.01f * x;
  x = acc1[2] + bias; o1.z = x > 0.f ? x : 0.01f * x;
  x = acc1[3] + bias; o1.w = x > 0.f ? x : 0.01f * x;
  *(float4*)&out[(size_t)(r0 + orow + 0) * DIM + c0] = o0;
  *(float4*)&out[(size_t)(r0 + orow + 1) * DIM + c0] = o1;
}

// ---------------- fused: h = relu(W comp + b); attw = tanh(h.hsA[r]); prot += attw*hsA/N ----------------
__global__ __launch_bounds__(256) void k_attprot(
    float* __restrict__ prot, const float* __restrict__ hsA,
    const float* __restrict__ comp, const float* __restrict__ W,
    const float* __restrict__ b) {
  __shared__ float cvec[DIM];
  __shared__ float hv_s[DIM];
  __shared__ float lw[32];
  __shared__ float red[256];
  int tid = threadIdx.x;
  int w = tid >> 6, lane = tid & 63;
  if (tid < 128) cvec[tid] = comp[tid];
  __syncthreads();
  if (tid < 128) {
    float acc = b[tid];
    #pragma unroll
    for (int k4 = 0; k4 < 32; ++k4) {
      float4 w4 = *(const float4*)&W[tid * DIM + k4 * 4];
      acc += cvec[k4*4+0] * w4.x + cvec[k4*4+1] * w4.y + cvec[k4*4+2] * w4.z + cvec[k4*4+3] * w4.w;
    }
    hv_s[tid] = acc > 0.f ? acc : 0.f;
  }
  __syncthreads();
  int r0 = blockIdx.x * 32;
  float2 hv = ((const float2*)hv_s)[lane];
  for (int rr = w; rr < 32; rr += 4) {
    float2 xv = ((const float2*)(hsA + (size_t)(r0 + rr) * DIM))[lane];
    float dt = hv.x * xv.x + hv.y * xv.y;
    for (int o = 32; o > 0; o >>= 1) dt += __shfl_xor(dt, o);
    if (lane == 0) lw[rr] = tanhf(dt);
  }
  __syncthreads();
  int d = tid & 127, half = tid >> 7;
  float acc = 0.f;
  for (int rr = half; rr < 32; rr += 2)
    acc += lw[rr] * hsA[(size_t)(r0 + rr) * DIM + d];
  red[tid] = acc;
  __syncthreads();
  if (half == 0) atomicAdd(&prot[d], (acc + red[tid + 128]) * (1.f / NWORDS));
}

// ---------------- output MLP: cat(256) -> 2x relu-linear(256) -> scalar ----------------
__global__ __launch_bounds__(256) void k_final(
    float* __restrict__ out, const float* __restrict__ comp, const float* __restrict__ prot,
    const float* __restrict__ Wo, const float* __restrict__ bo,
    const float* __restrict__ Wi, const float* __restrict__ bi) {
  __shared__ float cat[256];
  __shared__ float wred[4];
  int t = threadIdx.x;
  int w = t >> 6, lane = t & 63;
  cat[t] = t < 128 ? comp[t] : prot[t - 128];
  __syncthreads();
  for (int l = 0; l < 2; ++l) {
    const float* Wl = Wo + l * 256 * 256;
    float acc = bo[l * 256 + t];
    #pragma unroll 8
    for (int k4 = 0; k4 < 64; ++k4) {
      float4 w4 = *(const float4*)&Wl[t * 256 + k4 * 4];
      acc += cat[k4*4+0] * w4.x + cat[k4*4+1] * w4.y + cat[k4*4+2] * w4.z + cat[k4*4+3] * w4.w;
    }
    __syncthreads();
    cat[t] = acc > 0.f ? acc : 0.f;
    __syncthreads();
  }
  float r = cat[t] * Wi[t];
  for (int o = 32; o > 0; o >>= 1) r += __shfl_xor(r, o);
  if (lane == 0) wred[w] = r;
  __syncthreads();
  if (t == 0) out[0] = wred[0] + wred[1] + wred[2] + wred[3] + bi[0];
}

extern "C" void kernel_launch(void* const* d_in, const int* in_sizes, int n_in,
                              void* d_out, int out_size, void* d_ws, size_t ws_size,
                              hipStream_t stream) {
  const int*   fingerprints = (const int*)d_in[0];
  const float* adjacency    = (const float*)d_in[1];
  const int*   words        = (const int*)d_in[2];
  const float* emb_fp       = (const float*)d_in[3];
  const float* emb_word     = (const float*)d_in[4];
  const float* W_gnn_w      = (const float*)d_in[5];
  const float* W_gnn_b      = (const float*)d_in[6];
  const float* conv_w       = (const float*)d_in[7];
  const float* conv_b       = (const float*)d_in[8];
  const float* W_att_w      = (const float*)d_in[9];
  const float* W_att_b      = (const float*)d_in[10];
  const float* W_out_w      = (const float*)d_in[11];
  const float* W_out_b      = (const float*)d_in[12];
  const float* W_int_w      = (const float*)d_in[13];
  const float* W_int_b      = (const float*)d_in[14];
  float* out = (float*)d_out;

  float* xs   = (float*)d_ws;               // 524288
  float* hsb  = xs   + 524288;              // 524288
  float* valx = hsb  + 524288;              // 1048576
  float* pa   = valx + 1048576;             // 2097152
  float* pb   = pa   + 2097152;             // 2097152
  float* hsA  = pb   + 2097152;             // 2097152
  float* attw = hsA  + 2097152;             // 16384
  float* small= attw + 16384;               // 512
  int*   colx = (int*)(small + 512);        // 1048576
  int*   cntv = colx + 1048576;             // 4096
  float* comp = small, *prot = small + 128;
  (void)attw;

  hipMemsetAsync(small, 0, 512 * sizeof(float), stream);

  // ---- GNN ----
  k_gather<<<512, 256, 0, stream>>>(xs, emb_fp, fingerprints);
  k_adj_scan<<<1024, 256, 0, stream>>>(cntv, colx, valx, adjacency);
  for (int l = 0; l < 3; ++l) {
    k_linear_relu<<<128, 256, 0, stream>>>(hsb, xs, W_gnn_w + l * DIM * DIM, W_gnn_b + l * DIM);
    k_spmm<<<NA, 128, 0, stream>>>(xs, hsb, cntv, colx, valx, adjacency);
  }
  k_mean<<<128, 256, 0, stream>>>(comp, xs, 32, 1.0f / NA);

  // ---- protein CNN (layer 1 gathers emb_word[words] directly) ----
  k_conv<1><<<1024, 256, 0, stream>>>(pb, nullptr, words, emb_word, conv_w + 0 * 529, conv_b + 0);
  k_conv<0><<<1024, 256, 0, stream>>>(pa, pb, nullptr, nullptr, conv_w + 1 * 529, conv_b + 1);
  k_conv<0><<<1024, 256, 0, stream>>>(pb, pa, nullptr, nullptr, conv_w + 2 * 529, conv_b + 2);

  // ---- attention ----
  k_linear_relu<<<512, 256, 0, stream>>>(hsA, pb, W_att_w, W_att_b);
  k_attprot<<<512, 256, 0, stream>>>(prot, hsA, comp, W_att_w, W_att_b);

  // ---- output MLP ----
  k_final<<<1, 256, 0, stream>>>(out, comp, prot, W_out_w, W_out_b, W_int_w, W_int_b);
}

// Round 13
// 492.120 us; speedup vs baseline: 1.7411x; 1.7411x over previous
//
#include <hip/hip_runtime.h>

#define DIM 128
#define NA 4096
#define NWORDS 16384
#define MAXNZ 256
#define KW 23
#define PAD 11

// ---------------- gather rows: out[i][:] = tab[idx[i]][:] (float4) ----------------
__global__ void k_gather(float* __restrict__ out, const float* __restrict__ tab,
                         const int* __restrict__ idx) {
  int t = blockIdx.x * blockDim.x + threadIdx.x;   // over n*32 float4s
  int r = t >> 5, c = t & 31;
  ((float4*)out)[t] = ((const float4*)(tab + (size_t)idx[r] * DIM))[c];
}

// ---------------- adjacency scan -> per-row (col,val) lists ----------------
__global__ void k_adj_scan(int* __restrict__ cnt, int* __restrict__ colx,
                           float* __restrict__ valx, const float* __restrict__ adj) {
  int w = threadIdx.x >> 6, lane = threadIdx.x & 63;
  int row = blockIdx.x * 4 + w;
  const float4* ar = (const float4*)(adj + (size_t)row * NA);
  int count = 0;
  unsigned long long ltm = (1ull << lane) - 1ull;
  for (int c4 = lane; c4 < NA / 4; c4 += 64) {
    float4 v = ar[c4];
    #pragma unroll
    for (int e = 0; e < 4; ++e) {
      float ve = e == 0 ? v.x : e == 1 ? v.y : e == 2 ? v.z : v.w;
      unsigned long long m = __ballot(ve != 0.0f);
      if (ve != 0.0f) {
        int off = count + (int)__popcll(m & ltm);
        if (off < MAXNZ) { colx[row * MAXNZ + off] = c4 * 4 + e; valx[row * MAXNZ + off] = ve; }
      }
      count += (int)__popcll(m);
    }
  }
  if (lane == 0) cnt[row] = count;
}

// ---------------- C[M,128] = relu(A[M,128] @ W[128,128]^T + b) ----------------
__global__ __launch_bounds__(256) void k_linear_relu(
    float* __restrict__ out, const float* __restrict__ A,
    const float* __restrict__ W, const float* __restrict__ bias) {
  __shared__ float As[64 * 132];
  __shared__ float Ws[64 * 132];
  int mt = blockIdx.x >> 1, nt = blockIdx.x & 1;
  int r0 = mt * 64, c0 = nt * 64;
  int tid = threadIdx.x;
  for (int q = tid; q < 64 * 32; q += 256) {
    int row = q >> 5, c4 = q & 31;
    *(float4*)&As[row * 132 + c4 * 4] = *(const float4*)&A[(size_t)(r0 + row) * DIM + c4 * 4];
    *(float4*)&Ws[row * 132 + c4 * 4] = *(const float4*)&W[(size_t)(c0 + row) * DIM + c4 * 4];
  }
  __syncthreads();
  int rgr = tid & 15, cgr = tid >> 4;
  float acc[4][4] = {};
  #pragma unroll 4
  for (int k4 = 0; k4 < 32; ++k4) {
    int kk = ((k4 + rgr) & 31) * 4;
    float4 a[4], w[4];
    #pragma unroll
    for (int i = 0; i < 4; ++i) a[i] = *(const float4*)&As[(rgr * 4 + i) * 132 + kk];
    #pragma unroll
    for (int j = 0; j < 4; ++j) w[j] = *(const float4*)&Ws[(cgr * 4 + j) * 132 + kk];
    #pragma unroll
    for (int i = 0; i < 4; ++i)
      #pragma unroll
      for (int j = 0; j < 4; ++j)
        acc[i][j] += a[i].x * w[j].x + a[i].y * w[j].y + a[i].z * w[j].z + a[i].w * w[j].w;
  }
  #pragma unroll
  for (int i = 0; i < 4; ++i) {
    int r = r0 + rgr * 4 + i;
    int c = c0 + cgr * 4;
    float4 bv = *(const float4*)&bias[c];
    float4 o;
    o.x = acc[i][0] + bv.x; o.y = acc[i][1] + bv.y;
    o.z = acc[i][2] + bv.z; o.w = acc[i][3] + bv.w;
    o.x = o.x > 0.f ? o.x : 0.f; o.y = o.y > 0.f ? o.y : 0.f;
    o.z = o.z > 0.f ? o.z : 0.f; o.w = o.w > 0.f ? o.w : 0.f;
    *(float4*)&out[(size_t)r * DIM + c] = o;
  }
}

// ---------------- xs[r][:] += sum_i val_i * hs[col_i][:] ----------------
__global__ void k_spmm(float* __restrict__ xs, const float* __restrict__ hs,
                       const int* __restrict__ cnt, const int* __restrict__ colx,
                       const float* __restrict__ valx, const float* __restrict__ adj) {
  __shared__ int scol[MAXNZ];
  __shared__ float sval[MAXNZ];
  int r = blockIdx.x, d = threadIdx.x;
  int n = cnt[r];
  int m = (n <= MAXNZ) ? n : 0;
  for (int i = d; i < m; i += 128) {
    scol[i] = colx[r * MAXNZ + i];
    sval[i] = valx[r * MAXNZ + i];
  }
  __syncthreads();
  float acc = xs[(size_t)r * DIM + d];
  if (n <= MAXNZ) {
    for (int i = 0; i < n; ++i)
      acc += sval[i] * hs[(size_t)scol[i] * DIM + d];
  } else {              // safety fallback, statistically never taken
    for (int c = 0; c < NA; ++c) {
      float a = adj[(size_t)r * NA + c];
      if (a != 0.f) acc += a * hs[(size_t)c * DIM + d];
    }
  }
  xs[(size_t)r * DIM + d] = acc;
}

// ---------------- column mean (scaled), atomic partials ----------------
__global__ void k_mean(float* __restrict__ out, const float* __restrict__ in,
                       int rows_per_block, float scale) {
  __shared__ float red[256];
  int d = threadIdx.x & 127, half = threadIdx.x >> 7;
  int r0 = blockIdx.x * rows_per_block;
  float acc = 0.f;
  for (int r = r0 + half; r < r0 + rows_per_block; r += 2)
    acc += in[(size_t)r * DIM + d];
  red[threadIdx.x] = acc;
  __syncthreads();
  if (half == 0) atomicAdd(&out[d], (acc + red[threadIdx.x + 128]) * scale);
}

// ---------------- 23x23 conv (1 channel) + bias + leaky relu ----------------
// Thread = 4 cols x 2 rows; per dy each row window = 7 contiguous
// ds_read_b128 (lanes 0-31 contiguous 16B = canonical conflict-free).
// Rows roll (B at dy becomes the A-row of dy+1) -> 168 b128/thread vs
// round-9's 690 b32 (DS-issue binder). WINDOW = NAMED float4 VARIABLES
// (A0..A6,B0..B6) + preprocessor element table + 23 enumerated FMA lines:
// no local arrays at all, so SROA cannot fail (rounds 10/12: array windows
// live across the dy-loop spilled to scratch, WRITE_SIZE 595/860 MB).
#define CROWS 16
#define TROWS 38      // CROWS + 22
#define TCOLS 152     // tile col cc <-> global col cc-12 (left pad 12)
#define TSTR  152

#define AE1 A0.y
#define AE2 A0.z
#define AE3 A0.w
#define AE4 A1.x
#define AE5 A1.y
#define AE6 A1.z
#define AE7 A1.w
#define AE8 A2.x
#define AE9 A2.y
#define AE10 A2.z
#define AE11 A2.w
#define AE12 A3.x
#define AE13 A3.y
#define AE14 A3.z
#define AE15 A3.w
#define AE16 A4.x
#define AE17 A4.y
#define AE18 A4.z
#define AE19 A4.w
#define AE20 A5.x
#define AE21 A5.y
#define AE22 A5.z
#define AE23 A5.w
#define AE24 A6.x
#define AE25 A6.y
#define AE26 A6.z
#define BE1 B0.y
#define BE2 B0.z
#define BE3 B0.w
#define BE4 B1.x
#define BE5 B1.y
#define BE6 B1.z
#define BE7 B1.w
#define BE8 B2.x
#define BE9 B2.y
#define BE10 B2.z
#define BE11 B2.w
#define BE12 B3.x
#define BE13 B3.y
#define BE14 B3.z
#define BE15 B3.w
#define BE16 B4.x
#define BE17 B4.y
#define BE18 B4.z
#define BE19 B4.w
#define BE20 B5.x
#define BE21 B5.y
#define BE22 B5.z
#define BE23 B5.w
#define BE24 B6.x
#define BE25 B6.y
#define BE26 B6.z

#define FML(w_, p0,p1,p2,p3, q0,q1,q2,q3) \
  acc00 = __builtin_fmaf(w_, p0, acc00); acc01 = __builtin_fmaf(w_, p1, acc01); \
  acc02 = __builtin_fmaf(w_, p2, acc02); acc03 = __builtin_fmaf(w_, p3, acc03); \
  acc10 = __builtin_fmaf(w_, q0, acc10); acc11 = __builtin_fmaf(w_, q1, acc11); \
  acc12 = __builtin_fmaf(w_, q2, acc12); acc13 = __builtin_fmaf(w_, q3, acc13);

// P = window for output row orow (weight row dy), Q = window for orow+1.
#define CSTEP(wb, P, Q) { float w_; \
  w_=(wb)[0];  FML(w_, P##E1, P##E2, P##E3, P##E4,  Q##E1, Q##E2, Q##E3, Q##E4)  \
  w_=(wb)[1];  FML(w_, P##E2, P##E3, P##E4, P##E5,  Q##E2, Q##E3, Q##E4, Q##E5)  \
  w_=(wb)[2];  FML(w_, P##E3, P##E4, P##E5, P##E6,  Q##E3, Q##E4, Q##E5, Q##E6)  \
  w_=(wb)[3];  FML(w_, P##E4, P##E5, P##E6, P##E7,  Q##E4, Q##E5, Q##E6, Q##E7)  \
  w_=(wb)[4];  FML(w_, P##E5, P##E6, P##E7, P##E8,  Q##E5, Q##E6, Q##E7, Q##E8)  \
  w_=(wb)[5];  FML(w_, P##E6, P##E7, P##E8, P##E9,  Q##E6, Q##E7, Q##E8, Q##E9)  \
  w_=(wb)[6];  FML(w_, P##E7, P##E8, P##E9, P##E10, Q##E7, Q##E8, Q##E9, Q##E10) \
  w_=(wb)[7];  FML(w_, P##E8, P##E9, P##E10,P##E11, Q##E8, Q##E9, Q##E10,Q##E11) \
  w_=(wb)[8];  FML(w_, P##E9, P##E10,P##E11,P##E12, Q##E9, Q##E10,Q##E11,Q##E12) \
  w_=(wb)[9];  FML(w_, P##E10,P##E11,P##E12,P##E13, Q##E10,Q##E11,Q##E12,Q##E13) \
  w_=(wb)[10]; FML(w_, P##E11,P##E12,P##E13,P##E14, Q##E11,Q##E12,Q##E13,Q##E14) \
  w_=(wb)[11]; FML(w_, P##E12,P##E13,P##E14,P##E15, Q##E12,Q##E13,Q##E14,Q##E15) \
  w_=(wb)[12]; FML(w_, P##E13,P##E14,P##E15,P##E16, Q##E13,Q##E14,Q##E15,Q##E16) \
  w_=(wb)[13]; FML(w_, P##E14,P##E15,P##E16,P##E17, Q##E14,Q##E15,Q##E16,Q##E17) \
  w_=(wb)[14]; FML(w_, P##E15,P##E16,P##E17,P##E18, Q##E15,Q##E16,Q##E17,Q##E18) \
  w_=(wb)[15]; FML(w_, P##E16,P##E17,P##E18,P##E19, Q##E16,Q##E17,Q##E18,Q##E19) \
  w_=(wb)[16]; FML(w_, P##E17,P##E18,P##E19,P##E20, Q##E17,Q##E18,Q##E19,Q##E20) \
  w_=(wb)[17]; FML(w_, P##E18,P##E19,P##E20,P##E21, Q##E18,Q##E19,Q##E20,Q##E21) \
  w_=(wb)[18]; FML(w_, P##E19,P##E20,P##E21,P##E22, Q##E19,Q##E20,Q##E21,Q##E22) \
  w_=(wb)[19]; FML(w_, P##E20,P##E21,P##E22,P##E23, Q##E20,Q##E21,Q##E22,Q##E23) \
  w_=(wb)[20]; FML(w_, P##E21,P##E22,P##E23,P##E24, Q##E21,Q##E22,Q##E23,Q##E24) \
  w_=(wb)[21]; FML(w_, P##E22,P##E23,P##E24,P##E25, Q##E22,Q##E23,Q##E24,Q##E25) \
  w_=(wb)[22]; FML(w_, P##E23,P##E24,P##E25,P##E26, Q##E23,Q##E24,Q##E25,Q##E26) }

#define LOADA(trow) { const float4* p_ = (const float4*)&tile[(trow) * TSTR + c0]; \
  A0 = p_[0]; A1 = p_[1]; A2 = p_[2]; A3 = p_[3]; A4 = p_[4]; A5 = p_[5]; A6 = p_[6]; }
#define LOADB(trow) { const float4* p_ = (const float4*)&tile[(trow) * TSTR + c0]; \
  B0 = p_[0]; B1 = p_[1]; B2 = p_[2]; B3 = p_[3]; B4 = p_[4]; B5 = p_[5]; B6 = p_[6]; }

template<int GATHER>
__global__ __launch_bounds__(256, 4) void k_conv(
    float* __restrict__ out, const float* __restrict__ in,
    const int* __restrict__ words, const float* __restrict__ emb,
    const float* __restrict__ cw, const float* __restrict__ cb) {
  __shared__ float tile[TROWS * TSTR];   // 23.1 KB
  int r0 = blockIdx.x * CROWS;
  int tid = threadIdx.x;
  for (int p = tid; p < TROWS * TCOLS; p += 256) {
    int rr = p / TCOLS, cc = p - rr * TCOLS;
    int gr = r0 - PAD + rr, gc = cc - 12;
    float v = 0.f;
    if ((unsigned)gr < NWORDS && (unsigned)gc < DIM) {
      if (GATHER) v = emb[(size_t)words[gr] * DIM + gc];
      else        v = in[(size_t)gr * DIM + gc];
    }
    tile[rr * TSTR + cc] = v;
  }
  __syncthreads();
  int cg = tid & 31, rg = tid >> 5;   // 32 col-groups x 8 row-groups
  int c0 = cg * 4;                    // output cols c0..c0+3 (tile base col)
  int orow = rg * 2;                  // local output rows orow, orow+1
  float4 A0, A1, A2, A3, A4, A5, A6;
  float4 B0, B1, B2, B3, B4, B5, B6;
  float acc00 = 0.f, acc01 = 0.f, acc02 = 0.f, acc03 = 0.f;
  float acc10 = 0.f, acc11 = 0.f, acc12 = 0.f, acc13 = 0.f;

  LOADA(orow + 0)
  LOADB(orow + 1)
  const float* wr = cw;
  #pragma unroll 1
  for (int d2 = 0; d2 < 11; ++d2) {
    int dy = d2 * 2;
    CSTEP(wr, A, B)                    // weight row dy: rows orow+dy / +dy+1
    LOADA(orow + dy + 2)
    CSTEP(wr + KW, B, A)               // weight row dy+1
    LOADB(orow + dy + 3)
    wr += 2 * KW;
  }
  CSTEP(wr, A, B)                      // weight row 22

  float bias = cb[0];
  float4 o0, o1;
  float x;
  x = acc00 + bias; o0.x = x > 0.f ? x : 0.01f * x;
  x = acc01 + bias; o0.y = x > 0.f ? x : 0.01f * x;
  x = acc02 + bias; o0.z = x > 0.f ? x : 0.01f * x;
  x = acc03 + bias; o0.w = x > 0.f ? x : 0.01f * x;
  x = acc10 + bias; o1.x = x > 0.f ? x : 0.01f * x;
  x = acc11 + bias; o1.y = x > 0.f ? x : 0.01f * x;
  x = acc12 + bias; o1.z = x > 0.f ? x : 0.01f * x;
  x = acc13 + bias; o1.w = x > 0.f ? x : 0.01f * x;
  *(float4*)&out[(size_t)(r0 + orow + 0) * DIM + c0] = o0;
  *(float4*)&out[(size_t)(r0 + orow + 1) * DIM + c0] = o1;
}

// ---------------- fused: h = relu(W comp + b); attw = tanh(h.hsA[r]); prot += attw*hsA/N ----------------
__global__ __launch_bounds__(256) void k_attprot(
    float* __restrict__ prot, const float* __restrict__ hsA,
    const float* __restrict__ comp, const float* __restrict__ W,
    const float* __restrict__ b) {
  __shared__ float cvec[DIM];
  __shared__ float hv_s[DIM];
  __shared__ float lw[32];
  __shared__ float red[256];
  int tid = threadIdx.x;
  int w = tid >> 6, lane = tid & 63;
  if (tid < 128) cvec[tid] = comp[tid];
  __syncthreads();
  if (tid < 128) {
    float acc = b[tid];
    #pragma unroll
    for (int k4 = 0; k4 < 32; ++k4) {
      float4 w4 = *(const float4*)&W[tid * DIM + k4 * 4];
      acc += cvec[k4*4+0] * w4.x + cvec[k4*4+1] * w4.y + cvec[k4*4+2] * w4.z + cvec[k4*4+3] * w4.w;
    }
    hv_s[tid] = acc > 0.f ? acc : 0.f;
  }
  __syncthreads();
  int r0 = blockIdx.x * 32;
  float2 hv = ((const float2*)hv_s)[lane];
  for (int rr = w; rr < 32; rr += 4) {
    float2 xv = ((const float2*)(hsA + (size_t)(r0 + rr) * DIM))[lane];
    float dt = hv.x * xv.x + hv.y * xv.y;
    for (int o = 32; o > 0; o >>= 1) dt += __shfl_xor(dt, o);
    if (lane == 0) lw[rr] = tanhf(dt);
  }
  __syncthreads();
  int d = tid & 127, half = tid >> 7;
  float acc = 0.f;
  for (int rr = half; rr < 32; rr += 2)
    acc += lw[rr] * hsA[(size_t)(r0 + rr) * DIM + d];
  red[tid] = acc;
  __syncthreads();
  if (half == 0) atomicAdd(&prot[d], (acc + red[tid + 128]) * (1.f / NWORDS));
}

// ---------------- output MLP: cat(256) -> 2x relu-linear(256) -> scalar ----------------
__global__ __launch_bounds__(256) void k_final(
    float* __restrict__ out, const float* __restrict__ comp, const float* __restrict__ prot,
    const float* __restrict__ Wo, const float* __restrict__ bo,
    const float* __restrict__ Wi, const float* __restrict__ bi) {
  __shared__ float cat[256];
  __shared__ float wred[4];
  int t = threadIdx.x;
  int w = t >> 6, lane = t & 63;
  cat[t] = t < 128 ? comp[t] : prot[t - 128];
  __syncthreads();
  for (int l = 0; l < 2; ++l) {
    const float* Wl = Wo + l * 256 * 256;
    float acc = bo[l * 256 + t];
    #pragma unroll 8
    for (int k4 = 0; k4 < 64; ++k4) {
      float4 w4 = *(const float4*)&Wl[t * 256 + k4 * 4];
      acc += cat[k4*4+0] * w4.x + cat[k4*4+1] * w4.y + cat[k4*4+2] * w4.z + cat[k4*4+3] * w4.w;
    }
    __syncthreads();
    cat[t] = acc > 0.f ? acc : 0.f;
    __syncthreads();
  }
  float r = cat[t] * Wi[t];
  for (int o = 32; o > 0; o >>= 1) r += __shfl_xor(r, o);
  if (lane == 0) wred[w] = r;
  __syncthreads();
  if (t == 0) out[0] = wred[0] + wred[1] + wred[2] + wred[3] + bi[0];
}

extern "C" void kernel_launch(void* const* d_in, const int* in_sizes, int n_in,
                              void* d_out, int out_size, void* d_ws, size_t ws_size,
                              hipStream_t stream) {
  const int*   fingerprints = (const int*)d_in[0];
  const float* adjacency    = (const float*)d_in[1];
  const int*   words        = (const int*)d_in[2];
  const float* emb_fp       = (const float*)d_in[3];
  const float* emb_word     = (const float*)d_in[4];
  const float* W_gnn_w      = (const float*)d_in[5];
  const float* W_gnn_b      = (const float*)d_in[6];
  const float* conv_w       = (const float*)d_in[7];
  const float* conv_b       = (const float*)d_in[8];
  const float* W_att_w      = (const float*)d_in[9];
  const float* W_att_b      = (const float*)d_in[10];
  const float* W_out_w      = (const float*)d_in[11];
  const float* W_out_b      = (const float*)d_in[12];
  const float* W_int_w      = (const float*)d_in[13];
  const float* W_int_b      = (const float*)d_in[14];
  float* out = (float*)d_out;

  float* xs   = (float*)d_ws;               // 524288
  float* hsb  = xs   + 524288;              // 524288
  float* valx = hsb  + 524288;              // 1048576
  float* pa   = valx + 1048576;             // 2097152
  float* pb   = pa   + 2097152;             // 2097152
  float* hsA  = pb   + 2097152;             // 2097152
  float* attw = hsA  + 2097152;             // 16384
  float* small= attw + 16384;               // 512
  int*   colx = (int*)(small + 512);        // 1048576
  int*   cntv = colx + 1048576;             // 4096
  float* comp = small, *prot = small + 128;
  (void)attw; (void)pa;

  hipMemsetAsync(small, 0, 512 * sizeof(float), stream);

  // ---- GNN ----
  k_gather<<<512, 256, 0, stream>>>(xs, emb_fp, fingerprints);
  k_adj_scan<<<1024, 256, 0, stream>>>(cntv, colx, valx, adjacency);
  for (int l = 0; l < 3; ++l) {
    k_linear_relu<<<128, 256, 0, stream>>>(hsb, xs, W_gnn_w + l * DIM * DIM, W_gnn_b + l * DIM);
    k_spmm<<<NA, 128, 0, stream>>>(xs, hsb, cntv, colx, valx, adjacency);
  }
  k_mean<<<128, 256, 0, stream>>>(comp, xs, 32, 1.0f / NA);

  // ---- protein CNN (layer 1 gathers emb_word[words] directly) ----
  k_conv<1><<<1024, 256, 0, stream>>>(pb, nullptr, words, emb_word, conv_w + 0 * 529, conv_b + 0);
  k_conv<0><<<1024, 256, 0, stream>>>(pa, pb, nullptr, nullptr, conv_w + 1 * 529, conv_b + 1);
  k_conv<0><<<1024, 256, 0, stream>>>(pb, pa, nullptr, nullptr, conv_w + 2 * 529, conv_b + 2);

  // ---- attention ----
  k_linear_relu<<<512, 256, 0, stream>>>(hsA, pb, W_att_w, W_att_b);
  k_attprot<<<512, 256, 0, stream>>>(prot, hsA, comp, W_att_w, W_att_b);

  // ---- output MLP ----
  k_final<<<1, 256, 0, stream>>>(out, comp, prot, W_out_w, W_out_b, W_int_w, W_int_b);
}

// Round 15
// 363.813 us; speedup vs baseline: 2.3551x; 1.3527x over previous
//
#include <hip/hip_runtime.h>

#define DIM 128
#define NA 4096
#define NWORDS 16384
#define MAXNZ 256
#define KW 23
#define PAD 11

// ---------------- adjacency scan -> per-row (col,val) lists; also gathers xs ----------------
__global__ void k_adj_scan(int* __restrict__ cnt, int* __restrict__ colx,
                           float* __restrict__ valx, const float* __restrict__ adj,
                           float* __restrict__ xs, const float* __restrict__ emb_fp,
                           const int* __restrict__ fingerprints) {
  int w = threadIdx.x >> 6, lane = threadIdx.x & 63;
  int row = blockIdx.x * 4 + w;
  // fused gather: 128 threads move 4 rows x 32 float4
  if (threadIdx.x < 128) {
    int rr = blockIdx.x * 4 + (threadIdx.x >> 5), c4 = threadIdx.x & 31;
    ((float4*)(xs + (size_t)rr * DIM))[c4] =
        ((const float4*)(emb_fp + (size_t)fingerprints[rr] * DIM))[c4];
  }
  const float4* ar = (const float4*)(adj + (size_t)row * NA);
  int count = 0;
  unsigned long long ltm = (1ull << lane) - 1ull;
  for (int c4 = lane; c4 < NA / 4; c4 += 64) {
    float4 v = ar[c4];
    #pragma unroll
    for (int e = 0; e < 4; ++e) {
      float ve = e == 0 ? v.x : e == 1 ? v.y : e == 2 ? v.z : v.w;
      unsigned long long m = __ballot(ve != 0.0f);
      if (ve != 0.0f) {
        int off = count + (int)__popcll(m & ltm);
        if (off < MAXNZ) { colx[row * MAXNZ + off] = c4 * 4 + e; valx[row * MAXNZ + off] = ve; }
      }
      count += (int)__popcll(m);
    }
  }
  if (lane == 0) cnt[row] = count;
}

// ---------------- C[M,128] = relu(A[M,128] @ W[128,128]^T + b) ----------------
__global__ __launch_bounds__(256) void k_linear_relu(
    float* __restrict__ out, const float* __restrict__ A,
    const float* __restrict__ W, const float* __restrict__ bias) {
  __shared__ float As[64 * 132];
  __shared__ float Ws[64 * 132];
  int mt = blockIdx.x >> 1, nt = blockIdx.x & 1;
  int r0 = mt * 64, c0 = nt * 64;
  int tid = threadIdx.x;
  for (int q = tid; q < 64 * 32; q += 256) {
    int row = q >> 5, c4 = q & 31;
    *(float4*)&As[row * 132 + c4 * 4] = *(const float4*)&A[(size_t)(r0 + row) * DIM + c4 * 4];
    *(float4*)&Ws[row * 132 + c4 * 4] = *(const float4*)&W[(size_t)(c0 + row) * DIM + c4 * 4];
  }
  __syncthreads();
  int rgr = tid & 15, cgr = tid >> 4;
  float acc[4][4] = {};
  #pragma unroll 4
  for (int k4 = 0; k4 < 32; ++k4) {
    int kk = ((k4 + rgr) & 31) * 4;
    float4 a[4], w[4];
    #pragma unroll
    for (int i = 0; i < 4; ++i) a[i] = *(const float4*)&As[(rgr * 4 + i) * 132 + kk];
    #pragma unroll
    for (int j = 0; j < 4; ++j) w[j] = *(const float4*)&Ws[(cgr * 4 + j) * 132 + kk];
    #pragma unroll
    for (int i = 0; i < 4; ++i)
      #pragma unroll
      for (int j = 0; j < 4; ++j)
        acc[i][j] += a[i].x * w[j].x + a[i].y * w[j].y + a[i].z * w[j].z + a[i].w * w[j].w;
  }
  #pragma unroll
  for (int i = 0; i < 4; ++i) {
    int r = r0 + rgr * 4 + i;
    int c = c0 + cgr * 4;
    float4 bv = *(const float4*)&bias[c];
    float4 o;
    o.x = acc[i][0] + bv.x; o.y = acc[i][1] + bv.y;
    o.z = acc[i][2] + bv.z; o.w = acc[i][3] + bv.w;
    o.x = o.x > 0.f ? o.x : 0.f; o.y = o.y > 0.f ? o.y : 0.f;
    o.z = o.z > 0.f ? o.z : 0.f; o.w = o.w > 0.f ? o.w : 0.f;
    *(float4*)&out[(size_t)r * DIM + c] = o;
  }
}

// ---------------- xs[r][:] += sum_i val_i * hs[col_i][:] ----------------
__global__ void k_spmm(float* __restrict__ xs, const float* __restrict__ hs,
                       const int* __restrict__ cnt, const int* __restrict__ colx,
                       const float* __restrict__ valx, const float* __restrict__ adj) {
  __shared__ int scol[MAXNZ];
  __shared__ float sval[MAXNZ];
  int r = blockIdx.x, d = threadIdx.x;
  int n = cnt[r];
  int m = (n <= MAXNZ) ? n : 0;
  for (int i = d; i < m; i += 128) {
    scol[i] = colx[r * MAXNZ + i];
    sval[i] = valx[r * MAXNZ + i];
  }
  __syncthreads();
  float acc = xs[(size_t)r * DIM + d];
  if (n <= MAXNZ) {
    for (int i = 0; i < n; ++i)
      acc += sval[i] * hs[(size_t)scol[i] * DIM + d];
  } else {              // safety fallback, statistically never taken
    for (int c = 0; c < NA; ++c) {
      float a = adj[(size_t)r * NA + c];
      if (a != 0.f) acc += a * hs[(size_t)c * DIM + d];
    }
  }
  xs[(size_t)r * DIM + d] = acc;
}

// ---------------- column mean (scaled), atomic partials ----------------
__global__ void k_mean(float* __restrict__ out, const float* __restrict__ in,
                       int rows_per_block, float scale) {
  __shared__ float red[256];
  int d = threadIdx.x & 127, half = threadIdx.x >> 7;
  int r0 = blockIdx.x * rows_per_block;
  float acc = 0.f;
  for (int r = r0 + half; r < r0 + rows_per_block; r += 2)
    acc += in[(size_t)r * DIM + d];
  red[threadIdx.x] = acc;
  __syncthreads();
  if (half == 0) atomicAdd(&out[d], (acc + red[threadIdx.x + 128]) * scale);
}

// ---------------- 23x23 conv (1 channel) + bias + leaky relu ----------------
// COL-MAJOR tile tileT[col][row], row stride TSTRT=42 dwords (even -> b64
// aligned; gcd(42,32)=2 -> 16 banks x 2-way = free per m136). Thread =
// 1 col x 8 rows (round-9 assignment). Per dx the 30-row strip is
// CONTIGUOUS -> 15 ds_read_b64 (vs round-9's 30 b32; DS-issue was the
// 43us binder). Window v[30] is PER-ITERATION (dead at dx end) -> the
// only SROA-safe pattern (rounds 1/9 no-spill; all loop-carried windows
// spilled in rounds 10/12/13).
#define CROWS 16
#define TROWS 38      // CROWS + 22
#define TCOLS 150     // tile col cc <-> global col cc-11
#define TSTRT 42      // dwords per tile column (even, gcd(42,32)=2)
template<int GATHER>
__global__ __launch_bounds__(256, 4) void k_conv(
    float* __restrict__ out, const float* __restrict__ in,
    const int* __restrict__ words, const float* __restrict__ emb,
    const float* __restrict__ cw, const float* __restrict__ cb) {
  __shared__ float tileT[TCOLS * TSTRT];   // 25.2 KB
  int r0 = blockIdx.x * CROWS;
  int tid = threadIdx.x;
  for (int p = tid; p < TROWS * TCOLS; p += 256) {
    int rr = p / TCOLS, cc = p - rr * TCOLS;
    int gr = r0 - PAD + rr, gc = cc - PAD;
    float v = 0.f;
    if ((unsigned)gr < NWORDS && (unsigned)gc < DIM) {
      if (GATHER) v = emb[(size_t)words[gr] * DIM + gc];
      else        v = in[(size_t)gr * DIM + gc];
    }
    tileT[cc * TSTRT + rr] = v;
  }
  __syncthreads();
  int col = tid & 127, rb = tid >> 7;   // rb in {0,1}
  int rbase = rb * 8;                   // 8 output rows per thread
  float acc0 = 0.f, acc1 = 0.f, acc2 = 0.f, acc3 = 0.f;
  float acc4 = 0.f, acc5 = 0.f, acc6 = 0.f, acc7 = 0.f;
  for (int dx = 0; dx < KW; ++dx) {
    float v[30];                        // per-iteration: dead at loop end
    const float2* src = (const float2*)&tileT[(col + dx) * TSTRT + rbase];
    #pragma unroll
    for (int q = 0; q < 15; ++q) {
      float2 t_ = src[q];
      v[q * 2 + 0] = t_.x; v[q * 2 + 1] = t_.y;
    }
    const float* wp = cw + dx;          // wave-uniform -> s_loads
    #pragma unroll
    for (int dy = 0; dy < KW; ++dy) {
      float wv = wp[dy * KW];
      acc0 = __builtin_fmaf(wv, v[dy + 0], acc0);
      acc1 = __builtin_fmaf(wv, v[dy + 1], acc1);
      acc2 = __builtin_fmaf(wv, v[dy + 2], acc2);
      acc3 = __builtin_fmaf(wv, v[dy + 3], acc3);
      acc4 = __builtin_fmaf(wv, v[dy + 4], acc4);
      acc5 = __builtin_fmaf(wv, v[dy + 5], acc5);
      acc6 = __builtin_fmaf(wv, v[dy + 6], acc6);
      acc7 = __builtin_fmaf(wv, v[dy + 7], acc7);
    }
  }
  float bias = cb[0];
  size_t ob = (size_t)(r0 + rbase) * DIM + col;
  float x;
  x = acc0 + bias; out[ob + 0 * DIM] = x > 0.f ? x : 0.01f * x;
  x = acc1 + bias; out[ob + 1 * DIM] = x > 0.f ? x : 0.01f * x;
  x = acc2 + bias; out[ob + 2 * DIM] = x > 0.f ? x : 0.01f * x;
  x = acc3 + bias; out[ob + 3 * DIM] = x > 0.f ? x : 0.01f * x;
  x = acc4 + bias; out[ob + 4 * DIM] = x > 0.f ? x : 0.01f * x;
  x = acc5 + bias; out[ob + 5 * DIM] = x > 0.f ? x : 0.01f * x;
  x = acc6 + bias; out[ob + 6 * DIM] = x > 0.f ? x : 0.01f * x;
  x = acc7 + bias; out[ob + 7 * DIM] = x > 0.f ? x : 0.01f * x;
}

// ---------------- fused: h = relu(W comp + b); attw = tanh(h.hsA[r]); prot += attw*hsA/N ----------------
__global__ __launch_bounds__(256) void k_attprot(
    float* __restrict__ prot, const float* __restrict__ hsA,
    const float* __restrict__ comp, const float* __restrict__ W,
    const float* __restrict__ b) {
  __shared__ float cvec[DIM];
  __shared__ float hv_s[DIM];
  __shared__ float lw[32];
  __shared__ float red[256];
  int tid = threadIdx.x;
  int w = tid >> 6, lane = tid & 63;
  if (tid < 128) cvec[tid] = comp[tid];
  __syncthreads();
  if (tid < 128) {
    float acc = b[tid];
    #pragma unroll
    for (int k4 = 0; k4 < 32; ++k4) {
      float4 w4 = *(const float4*)&W[tid * DIM + k4 * 4];
      acc += cvec[k4*4+0] * w4.x + cvec[k4*4+1] * w4.y + cvec[k4*4+2] * w4.z + cvec[k4*4+3] * w4.w;
    }
    hv_s[tid] = acc > 0.f ? acc : 0.f;
  }
  __syncthreads();
  int r0 = blockIdx.x * 32;
  float2 hv = ((const float2*)hv_s)[lane];
  for (int rr = w; rr < 32; rr += 4) {
    float2 xv = ((const float2*)(hsA + (size_t)(r0 + rr) * DIM))[lane];
    float dt = hv.x * xv.x + hv.y * xv.y;
    for (int o = 32; o > 0; o >>= 1) dt += __shfl_xor(dt, o);
    if (lane == 0) lw[rr] = tanhf(dt);
  }
  __syncthreads();
  int d = tid & 127, half = tid >> 7;
  float acc = 0.f;
  for (int rr = half; rr < 32; rr += 2)
    acc += lw[rr] * hsA[(size_t)(r0 + rr) * DIM + d];
  red[tid] = acc;
  __syncthreads();
  if (half == 0) atomicAdd(&prot[d], (acc + red[tid + 128]) * (1.f / NWORDS));
}

// ---------------- output MLP: cat(256) -> 2x relu-linear(256) -> scalar ----------------
__global__ __launch_bounds__(256) void k_final(
    float* __restrict__ out, const float* __restrict__ comp, const float* __restrict__ prot,
    const float* __restrict__ Wo, const float* __restrict__ bo,
    const float* __restrict__ Wi, const float* __restrict__ bi) {
  __shared__ float cat[256];
  __shared__ float wred[4];
  int t = threadIdx.x;
  int w = t >> 6, lane = t & 63;
  cat[t] = t < 128 ? comp[t] : prot[t - 128];
  __syncthreads();
  for (int l = 0; l < 2; ++l) {
    const float* Wl = Wo + l * 256 * 256;
    float acc = bo[l * 256 + t];
    #pragma unroll 8
    for (int k4 = 0; k4 < 64; ++k4) {
      float4 w4 = *(const float4*)&Wl[t * 256 + k4 * 4];
      acc += cat[k4*4+0] * w4.x + cat[k4*4+1] * w4.y + cat[k4*4+2] * w4.z + cat[k4*4+3] * w4.w;
    }
    __syncthreads();
    cat[t] = acc > 0.f ? acc : 0.f;
    __syncthreads();
  }
  float r = cat[t] * Wi[t];
  for (int o = 32; o > 0; o >>= 1) r += __shfl_xor(r, o);
  if (lane == 0) wred[w] = r;
  __syncthreads();
  if (t == 0) out[0] = wred[0] + wred[1] + wred[2] + wred[3] + bi[0];
}

extern "C" void kernel_launch(void* const* d_in, const int* in_sizes, int n_in,
                              void* d_out, int out_size, void* d_ws, size_t ws_size,
                              hipStream_t stream) {
  const int*   fingerprints = (const int*)d_in[0];
  const float* adjacency    = (const float*)d_in[1];
  const int*   words        = (const int*)d_in[2];
  const float* emb_fp       = (const float*)d_in[3];
  const float* emb_word     = (const float*)d_in[4];
  const float* W_gnn_w      = (const float*)d_in[5];
  const float* W_gnn_b      = (const float*)d_in[6];
  const float* conv_w       = (const float*)d_in[7];
  const float* conv_b       = (const float*)d_in[8];
  const float* W_att_w      = (const float*)d_in[9];
  const float* W_att_b      = (const float*)d_in[10];
  const float* W_out_w      = (const float*)d_in[11];
  const float* W_out_b      = (const float*)d_in[12];
  const float* W_int_w      = (const float*)d_in[13];
  const float* W_int_b      = (const float*)d_in[14];
  float* out = (float*)d_out;

  float* xs   = (float*)d_ws;               // 524288
  float* hsb  = xs   + 524288;              // 524288
  float* valx = hsb  + 524288;              // 1048576
  float* pa   = valx + 1048576;             // 2097152
  float* pb   = pa   + 2097152;             // 2097152
  float* hsA  = pb   + 2097152;             // 2097152
  float* attw = hsA  + 2097152;             // 16384
  float* small= attw + 16384;               // 512
  int*   colx = (int*)(small + 512);        // 1048576
  int*   cntv = colx + 1048576;             // 4096
  float* comp = small, *prot = small + 128;
  (void)attw;

  hipMemsetAsync(small, 0, 512 * sizeof(float), stream);

  // ---- GNN (adj_scan also gathers xs) ----
  k_adj_scan<<<1024, 256, 0, stream>>>(cntv, colx, valx, adjacency, xs, emb_fp, fingerprints);
  for (int l = 0; l < 3; ++l) {
    k_linear_relu<<<128, 256, 0, stream>>>(hsb, xs, W_gnn_w + l * DIM * DIM, W_gnn_b + l * DIM);
    k_spmm<<<NA, 128, 0, stream>>>(xs, hsb, cntv, colx, valx, adjacency);
  }
  k_mean<<<128, 256, 0, stream>>>(comp, xs, 32, 1.0f / NA);

  // ---- protein CNN (layer 1 gathers emb_word[words] in staging) ----
  k_conv<1><<<1024, 256, 0, stream>>>(pb, nullptr, words, emb_word, conv_w + 0 * 529, conv_b + 0);
  k_conv<0><<<1024, 256, 0, stream>>>(pa, pb, nullptr, nullptr, conv_w + 1 * 529, conv_b + 1);
  k_conv<0><<<1024, 256, 0, stream>>>(pb, pa, nullptr, nullptr, conv_w + 2 * 529, conv_b + 2);

  // ---- attention ----
  k_linear_relu<<<512, 256, 0, stream>>>(hsA, pb, W_att_w, W_att_b);
  k_attprot<<<512, 256, 0, stream>>>(prot, hsA, comp, W_att_w, W_att_b);

  // ---- output MLP ----
  k_final<<<1, 256, 0, stream>>>(out, comp, prot, W_out_w, W_out_b, W_int_w, W_int_b);
}